// Round 1
// baseline (156.232 us; speedup 1.0000x reference)
//
#include <hip/hip_runtime.h>
#include <hip/hip_bf16.h>

typedef _Float16 f16;
typedef _Float16 f16x4 __attribute__((ext_vector_type(4)));
typedef _Float16 f16x8 __attribute__((ext_vector_type(8)));
typedef float f32x4 __attribute__((ext_vector_type(4)));

#define T_TOK 4096
#define V_N 32
#define H_N 256
#define LN_EPS_F 1e-5f

// ---------------- prep: W2,Wg [v][k][n] f32 -> [v][n][k] f16 ----------------
__global__ __launch_bounds__(256) void prep_transpose(
    const float* __restrict__ W2, const float* __restrict__ Wg,
    f16* __restrict__ W2t, f16* __restrict__ Wgt)
{
    __shared__ float tile[64][65];
    int bid = blockIdx.x;
    int w = bid >> 9;           // 0:W2 1:Wg
    int rem = bid & 511;
    int v = rem >> 4;
    int kt = (rem >> 2) & 3;
    int nt = rem & 3;
    const float* src = w ? Wg : W2;
    f16* dst = w ? Wgt : W2t;
    const float* base = src + ((size_t)v * H_N + (size_t)kt * 64) * H_N + nt * 64;
    int tid = threadIdx.x;
    #pragma unroll
    for (int p = 0; p < 16; ++p) {
        int idx = p * 256 + tid;
        int r = idx >> 6, c = idx & 63;
        tile[r][c] = base[(size_t)r * H_N + c];
    }
    __syncthreads();
    f16* obase = dst + ((size_t)v * H_N + (size_t)nt * 64) * H_N + kt * 64;
    #pragma unroll
    for (int p = 0; p < 16; ++p) {
        int idx = p * 256 + tid;
        int r = idx >> 6, c = idx & 63;
        obase[(size_t)r * H_N + c] = (f16)tile[c][r];
    }
}

// ---------------- GEMM1: H2 = relu(x*W1+b1) @ W2 + b2  (f16 out) ----------------
// grid: 32v * 32mt * 2nt = 2048 blocks, 256 thr (4 waves 2x2), tile 128x128, BK=64
__global__ __launch_bounds__(256) void gemm1(
    const float* __restrict__ x,   // [T][V]
    const float* __restrict__ W1,  // [V][H]
    const float* __restrict__ b1,
    const f16*  __restrict__ W2t,  // [V][n][k]
    const float* __restrict__ b2,
    f16* __restrict__ H2)          // [V][T][H]
{
    __shared__ f16 Ah[128][72];
    __shared__ f16 Bh[128][72];
    int bid = blockIdx.x;
    int v  = bid >> 6;
    int mt = (bid >> 1) & 31;
    int nt = bid & 1;
    int tid = threadIdx.x;
    int wid = tid >> 6, lane = tid & 63;
    int wr = wid >> 1, wc = wid & 1;
    int lo = lane & 15, hi = lane >> 4;
    int kg = tid & 7;
    int r0 = tid >> 3;              // 0..31

    f32x4 acc[4][4] = {};

    const float* W1v = W1 + v * H_N;
    const float* b1v = b1 + v * H_N;
    const f16* Bsrc = W2t + ((size_t)v * H_N + (size_t)nt * 128) * H_N;
    int m0 = mt * 128;

    for (int kt = 0; kt < 4; ++kt) {
        int kk0 = kt * 64;
        float w1r[8], b1r[8];
        #pragma unroll
        for (int j = 0; j < 8; ++j) {
            w1r[j] = W1v[kk0 + kg * 8 + j];
            b1r[j] = b1v[kk0 + kg * 8 + j];
        }
        #pragma unroll
        for (int p = 0; p < 4; ++p) {
            int row = r0 + p * 32;
            float xv = x[(size_t)(m0 + row) * V_N + v];
            f16x8 av;
            #pragma unroll
            for (int j = 0; j < 8; ++j) {
                float h = fmaf(xv, w1r[j], b1r[j]);
                av[j] = (f16)(h > 0.f ? h : 0.f);
            }
            *(f16x8*)&Ah[row][kg * 8] = av;
        }
        #pragma unroll
        for (int p = 0; p < 4; ++p) {
            int j = r0 + p * 32;
            *(f16x8*)&Bh[j][kg * 8] =
                *(const f16x8*)&Bsrc[(size_t)j * H_N + kk0 + kg * 8];
        }
        __syncthreads();
        #pragma unroll
        for (int ks = 0; ks < 2; ++ks) {
            f16x8 af[4], bf[4];
            #pragma unroll
            for (int rb = 0; rb < 4; ++rb)
                af[rb] = *(const f16x8*)&Ah[wr*64 + rb*16 + lo][ks*32 + hi*8];
            #pragma unroll
            for (int cb = 0; cb < 4; ++cb)
                bf[cb] = *(const f16x8*)&Bh[wc*64 + cb*16 + lo][ks*32 + hi*8];
            #pragma unroll
            for (int rb = 0; rb < 4; ++rb) {
                #pragma unroll
                for (int cb = 0; cb < 4; ++cb)
                    acc[rb][cb] = __builtin_amdgcn_mfma_f32_16x16x32_f16(
                        af[rb], bf[cb], acc[rb][cb], 0, 0, 0);
            }
        }
        __syncthreads();
    }

    f16* Hv = H2 + (size_t)v * T_TOK * H_N;
    #pragma unroll
    for (int rb = 0; rb < 4; ++rb) {
        #pragma unroll
        for (int cb = 0; cb < 4; ++cb) {
            int n = nt * 128 + wc * 64 + cb * 16 + lo;
            float bias = b2[v * H_N + n];
            #pragma unroll
            for (int reg = 0; reg < 4; ++reg) {
                int m = m0 + wr * 64 + rb * 16 + hi * 4 + reg;
                Hv[(size_t)m * H_N + n] = (f16)(acc[rb][cb][reg] + bias);
            }
        }
    }
}

// ---------------- GEMM2: gated = sigmoid(H2@Wg+bg)*H2, in-place over H2 ----------------
// grid: 32v * 32mt = 1024 blocks, 512 thr (8 waves 2x4), tile 128x256, BK=64
__global__ __launch_bounds__(512) void gemm2(
    f16* H2,                        // [V][T][H], read + overwritten (no restrict)
    const f16*  __restrict__ Wgt,   // [V][n][k]
    const float* __restrict__ bg)
{
    __shared__ f16 Ah[128][72];
    __shared__ f16 Bh[256][72];
    int bid = blockIdx.x;
    int v  = bid >> 5;
    int mt = bid & 31;
    int tid = threadIdx.x;
    int wid = tid >> 6, lane = tid & 63;
    int wr = wid >> 2, wc = wid & 3;
    int lo = lane & 15, hi = lane >> 4;
    int kg = tid & 7;
    int r0 = tid >> 3;              // 0..63

    f32x4 acc[4][4] = {};

    f16* Av = H2 + (size_t)v * T_TOK * H_N;
    const f16* Bsrc = Wgt + (size_t)v * H_N * H_N;
    int m0 = mt * 128;

    for (int kt = 0; kt < 4; ++kt) {
        int kk0 = kt * 64;
        #pragma unroll
        for (int p = 0; p < 2; ++p) {
            int row = r0 + p * 64;
            *(f16x8*)&Ah[row][kg * 8] =
                *(const f16x8*)&Av[(size_t)(m0 + row) * H_N + kk0 + kg * 8];
        }
        #pragma unroll
        for (int p = 0; p < 4; ++p) {
            int j = r0 + p * 64;
            *(f16x8*)&Bh[j][kg * 8] =
                *(const f16x8*)&Bsrc[(size_t)j * H_N + kk0 + kg * 8];
        }
        __syncthreads();
        #pragma unroll
        for (int ks = 0; ks < 2; ++ks) {
            f16x8 af[4], bf[4];
            #pragma unroll
            for (int rb = 0; rb < 4; ++rb)
                af[rb] = *(const f16x8*)&Ah[wr*64 + rb*16 + lo][ks*32 + hi*8];
            #pragma unroll
            for (int cb = 0; cb < 4; ++cb)
                bf[cb] = *(const f16x8*)&Bh[wc*64 + cb*16 + lo][ks*32 + hi*8];
            #pragma unroll
            for (int rb = 0; rb < 4; ++rb) {
                #pragma unroll
                for (int cb = 0; cb < 4; ++cb)
                    acc[rb][cb] = __builtin_amdgcn_mfma_f32_16x16x32_f16(
                        af[rb], bf[cb], acc[rb][cb], 0, 0, 0);
            }
        }
        __syncthreads();
    }

    // epilogue: each lane reads its own element then overwrites it (no race)
    #pragma unroll
    for (int rb = 0; rb < 4; ++rb) {
        #pragma unroll
        for (int cb = 0; cb < 4; ++cb) {
            int n = wc * 64 + cb * 16 + lo;
            float bias = bg[v * H_N + n];
            #pragma unroll
            for (int reg = 0; reg < 4; ++reg) {
                int m = m0 + wr * 64 + rb * 16 + hi * 4 + reg;
                size_t idx = (size_t)m * H_N + n;
                float a = acc[rb][cb][reg] + bias;
                float g = 1.f / (1.f + __expf(-a));
                float h2v = (float)Av[idx];
                Av[idx] = (f16)(g * h2v);
            }
        }
    }
}

// ---------------- LN + score, in-place. wave per row ----------------
__global__ __launch_bounds__(256) void ln_score(
    f16* GIO,                       // [V][T][H]: reads gated, writes var_outputs
    const float* __restrict__ gamma, const float* __restrict__ beta,
    const float* __restrict__ Wa, const float* __restrict__ ba,
    float* __restrict__ scores)     // [T][V]
{
    int R = blockIdx.x * 4 + (threadIdx.x >> 6);   // v*T + t
    int lane = threadIdx.x & 63;
    int v = R >> 12;
    int t = R & 4095;
    f16* row = GIO + (size_t)R * H_N;
    f16x4 gv = *(const f16x4*)&row[lane * 4];
    float g0 = gv[0], g1 = gv[1], g2 = gv[2], g3 = gv[3];
    float s = g0 + g1 + g2 + g3;
    float q = g0*g0 + g1*g1 + g2*g2 + g3*g3;
    #pragma unroll
    for (int m = 1; m < 64; m <<= 1) {
        s += __shfl_xor(s, m, 64);
        q += __shfl_xor(q, m, 64);
    }
    float mu = s * (1.f / 256.f);
    float var = q * (1.f / 256.f) - mu * mu;
    float inv = rsqrtf(var + LN_EPS_F);
    const float* gm = gamma + v * H_N + lane * 4;
    const float* bt = beta  + v * H_N + lane * 4;
    const float* wa = Wa + lane * 4;
    float o0 = (g0 - mu) * inv * gm[0] + bt[0];
    float o1 = (g1 - mu) * inv * gm[1] + bt[1];
    float o2 = (g2 - mu) * inv * gm[2] + bt[2];
    float o3 = (g3 - mu) * inv * gm[3] + bt[3];
    f16x4 ov = { (f16)o0, (f16)o1, (f16)o2, (f16)o3 };
    *(f16x4*)&row[lane * 4] = ov;
    float sp = o0*wa[0] + o1*wa[1] + o2*wa[2] + o3*wa[3];
    #pragma unroll
    for (int m = 1; m < 64; m <<= 1) sp += __shfl_xor(sp, m, 64);
    if (lane == 0) scores[t * V_N + v] = sp + ba[0];
}

// ---------------- softmax over V + pooled sum ----------------
__global__ __launch_bounds__(256) void pool(
    const f16* __restrict__ VO,     // [V][T][H]
    const float* __restrict__ scores, // [T][V]
    float* __restrict__ out)        // [T*H] vsn, then [T*V] attn
{
    int t = blockIdx.x, tid = threadIdx.x;
    __shared__ float sc[V_N];
    if (tid < V_N) sc[tid] = scores[t * V_N + tid];
    __syncthreads();
    float mx = -1e30f;
    #pragma unroll
    for (int v = 0; v < V_N; ++v) mx = fmaxf(mx, sc[v]);
    float e[V_N];
    float sum = 0.f;
    #pragma unroll
    for (int v = 0; v < V_N; ++v) { e[v] = __expf(sc[v] - mx); sum += e[v]; }
    float isum = 1.f / sum;
    float accv = 0.f;
    #pragma unroll
    for (int v = 0; v < V_N; ++v)
        accv += (float)VO[((size_t)v * T_TOK + t) * H_N + tid] * (e[v] * isum);
    out[(size_t)t * H_N + tid] = accv;
    if (tid < V_N)
        out[(size_t)T_TOK * H_N + (size_t)t * V_N + tid] = e[tid] * isum;
}

extern "C" void kernel_launch(void* const* d_in, const int* in_sizes, int n_in,
                              void* d_out, int out_size, void* d_ws, size_t ws_size,
                              hipStream_t stream)
{
    const float* x     = (const float*)d_in[0];
    const float* W1    = (const float*)d_in[1];
    const float* b1    = (const float*)d_in[2];
    const float* W2    = (const float*)d_in[3];
    const float* b2    = (const float*)d_in[4];
    const float* Wg    = (const float*)d_in[5];
    const float* bg    = (const float*)d_in[6];
    const float* gamma = (const float*)d_in[7];
    const float* beta  = (const float*)d_in[8];
    const float* Wa    = (const float*)d_in[9];
    const float* ba    = (const float*)d_in[10];
    float* out = (float*)d_out;

    char* ws = (char*)d_ws;
    f16* W2t = (f16*)ws;                               // 4 MB
    f16* Wgt = (f16*)(ws + ((size_t)4 << 20));         // 4 MB
    f16* H2  = (f16*)(ws + ((size_t)8 << 20));         // 64 MB
    float* scores = (float*)(ws + ((size_t)72 << 20)); // 0.5 MB

    prep_transpose<<<1024, 256, 0, stream>>>(W2, Wg, W2t, Wgt);
    gemm1<<<2048, 256, 0, stream>>>(x, W1, b1, W2t, b2, H2);
    gemm2<<<1024, 512, 0, stream>>>(H2, Wgt, bg);
    ln_score<<<32768, 256, 0, stream>>>(H2, gamma, beta, Wa, ba, scores);
    pool<<<4096, 256, 0, stream>>>(H2, scores, out);
}

// Round 2
// 122.058 us; speedup vs baseline: 1.2800x; 1.2800x over previous
//
#include <hip/hip_runtime.h>
#include <hip/hip_bf16.h>

typedef _Float16 f16;
typedef _Float16 f16x2 __attribute__((ext_vector_type(2)));
typedef _Float16 f16x4 __attribute__((ext_vector_type(4)));
typedef _Float16 f16x8 __attribute__((ext_vector_type(8)));
typedef float f32x4 __attribute__((ext_vector_type(4)));

#define T_TOK 4096
#define V_N 32
#define H_N 256
#define LN_EPS_F 1e-5f
#define PADH 264   // f16: 528B row stride; mult of 16B; odd-bank-group -> even b128 banking

__device__ __forceinline__ void gload16(const f16* g, f16* l) {
    __builtin_amdgcn_global_load_lds(
        (const __attribute__((address_space(1))) void*)g,
        (__attribute__((address_space(3))) void*)l, 16, 0, 0);
}

// ---------------- prep: W2,Wg [v][k][n] f32 -> [v][n][k] f16 ----------------
__global__ __launch_bounds__(256) void prep_transpose(
    const float* __restrict__ W2, const float* __restrict__ Wg,
    f16* __restrict__ W2t, f16* __restrict__ Wgt)
{
    __shared__ float tile[64][65];
    int bid = blockIdx.x;
    int w = bid >> 9;
    int rem = bid & 511;
    int v = rem >> 4;
    int kt = (rem >> 2) & 3;
    int nt = rem & 3;
    const float* src = w ? Wg : W2;
    f16* dst = w ? Wgt : W2t;
    const float* base = src + ((size_t)v * H_N + (size_t)kt * 64) * H_N + nt * 64;
    int tid = threadIdx.x;
    #pragma unroll
    for (int p = 0; p < 16; ++p) {
        int idx = p * 256 + tid;
        int r = idx >> 6, c = idx & 63;
        tile[r][c] = base[(size_t)r * H_N + c];
    }
    __syncthreads();
    f16* obase = dst + ((size_t)v * H_N + (size_t)nt * 64) * H_N + kt * 64;
    #pragma unroll
    for (int p = 0; p < 16; ++p) {
        int idx = p * 256 + tid;
        int r = idx >> 6, c = idx & 63;
        obase[(size_t)r * H_N + c] = (f16)tile[c][r];
    }
}

// ---------------- fused GRN: h1 -> H2 -> gated -> LN -> score, one pass ----------------
// grid 1024 = (v,mt), 512 thr (8 waves, 2M x 4N), tile 128 rows x full H=256
__global__ __launch_bounds__(512, 2) void fused_grn(
    const float* __restrict__ x,   // [T][V]
    const float* __restrict__ W1, const float* __restrict__ b1,
    const f16* __restrict__ W2t, const float* __restrict__ b2,
    const f16* __restrict__ Wgt, const float* __restrict__ bg,
    const float* __restrict__ gamma, const float* __restrict__ beta,
    const float* __restrict__ Wa, const float* __restrict__ ba,
    f16* __restrict__ VO,          // [V][T][H]
    float* __restrict__ scores)    // [T][V]
{
    __shared__ f16 Hs[128][PADH];       // h1, then H2, then gated  (67.6 KB)
    __shared__ f16 Bb[2][256 * 64];     // B double-buffer, linear + XOR chunk swizzle (64 KB)

    int bid = blockIdx.x;
    // XCD-grouped: each XCD owns 4 variables -> weights stay L2-local
    int xcd = bid & 7, r = bid >> 3;
    int v  = (xcd << 2) + (r >> 5);
    int mt = r & 31;
    int m0 = mt * 128;

    int tid = threadIdx.x;
    int wid = tid >> 6, lane = tid & 63;
    int wr = wid >> 2, wc = wid & 3;
    int lo = lane & 15, hi = lane >> 4;

    const f16* BW2 = W2t + (size_t)v * (H_N * H_N);
    const f16* BWg = Wgt + (size_t)v * (H_N * H_N);

    // stage one 256x64 f16 B-tile into Bb[buf] via global_load_lds, 16B/lane.
    // LDS chunk (row rr, chunk c) receives source k-chunk c^(rr&7); reader XORs too.
    auto stage = [&](const f16* B, int kk0, int buf) {
        #pragma unroll
        for (int i = 0; i < 4; ++i) {
            int rsub = lane >> 3;                     // rr & 7
            int rr = (wid << 5) + (i << 3) + rsub;
            int cs = (lane & 7) ^ rsub;
            gload16(B + (size_t)rr * H_N + kk0 + cs * 8,
                    &Bb[buf][(wid << 11) + (i << 9)]);
        }
    };

    f32x4 acc[4][4] = {};
    const f32x4 zero4 = {0.f, 0.f, 0.f, 0.f};

#define GEMM_STEP(BUF, KT)                                                         \
    {                                                                              \
        _Pragma("unroll")                                                          \
        for (int ks = 0; ks < 2; ++ks) {                                           \
            f16x8 af[4], bf[4];                                                    \
            _Pragma("unroll")                                                      \
            for (int rb = 0; rb < 4; ++rb)                                         \
                af[rb] = *(const f16x8*)&Hs[wr * 64 + rb * 16 + lo]                \
                                           [(KT) * 64 + ks * 32 + hi * 8];         \
            _Pragma("unroll")                                                      \
            for (int cb = 0; cb < 4; ++cb) {                                       \
                int n = wc * 64 + cb * 16 + lo;                                    \
                int ch = (ks * 4 + hi) ^ (lo & 7);                                 \
                bf[cb] = *(const f16x8*)&Bb[BUF][n * 64 + ch * 8];                 \
            }                                                                      \
            _Pragma("unroll")                                                      \
            for (int rb = 0; rb < 4; ++rb)                                         \
                _Pragma("unroll")                                                  \
                for (int cb = 0; cb < 4; ++cb)                                     \
                    acc[rb][cb] = __builtin_amdgcn_mfma_f32_16x16x32_f16(          \
                        af[rb], bf[cb], acc[rb][cb], 0, 0, 0);                     \
        }                                                                          \
    }

    // ---- prologue: issue W2 tile 0; generate h1 into Hs meanwhile ----
    stage(BW2, 0, 0);
    {
        int r0 = tid >> 3;          // 0..63
        int kg = tid & 7;
        const float* W1v = W1 + v * H_N;
        const float* b1v = b1 + v * H_N;
        float xv0 = x[(size_t)(m0 + r0) * V_N + v];
        float xv1 = x[(size_t)(m0 + r0 + 64) * V_N + v];
        #pragma unroll
        for (int kt = 0; kt < 4; ++kt) {
            int k0 = kt * 64 + kg * 8;
            f16x8 a0, a1;
            #pragma unroll
            for (int j = 0; j < 8; ++j) {
                float w = W1v[k0 + j], b = b1v[k0 + j];
                float h0 = fmaf(xv0, w, b);
                float h1 = fmaf(xv1, w, b);
                a0[j] = (f16)(h0 > 0.f ? h0 : 0.f);
                a1[j] = (f16)(h1 > 0.f ? h1 : 0.f);
            }
            *(f16x8*)&Hs[r0][k0] = a0;
            *(f16x8*)&Hs[r0 + 64][k0] = a1;
        }
    }
    __syncthreads();

    // ---- GEMM1: acc = h1 @ W2 ----
    #pragma unroll
    for (int kt = 0; kt < 4; ++kt) {
        if (kt < 3) stage(BW2, (kt + 1) * 64, (kt + 1) & 1);
        else        stage(BWg, 0, 0);            // prefetch GEMM2 tile 0
        GEMM_STEP(kt & 1, kt)
        __syncthreads();
    }

    // ---- H2 = acc + b2 -> Hs (f16); re-zero acc ----
    #pragma unroll
    for (int cb = 0; cb < 4; ++cb) {
        int n = wc * 64 + cb * 16 + lo;
        float bias = b2[v * H_N + n];
        #pragma unroll
        for (int rb = 0; rb < 4; ++rb) {
            #pragma unroll
            for (int reg = 0; reg < 4; ++reg) {
                int m = wr * 64 + rb * 16 + hi * 4 + reg;
                Hs[m][n] = (f16)(acc[rb][cb][reg] + bias);
                acc[rb][cb][reg] = 0.f;
            }
        }
    }
    __syncthreads();

    // ---- GEMM2: acc = H2 @ Wg ----
    #pragma unroll
    for (int kt = 0; kt < 4; ++kt) {
        if (kt < 3) stage(BWg, (kt + 1) * 64, (kt + 1) & 1);
        GEMM_STEP(kt & 1, kt)
        __syncthreads();
    }

    // ---- gated = sigmoid(acc+bg) * H2, back into Hs (own-lane, no race) ----
    #pragma unroll
    for (int cb = 0; cb < 4; ++cb) {
        int n = wc * 64 + cb * 16 + lo;
        float bias = bg[v * H_N + n];
        #pragma unroll
        for (int rb = 0; rb < 4; ++rb) {
            #pragma unroll
            for (int reg = 0; reg < 4; ++reg) {
                int m = wr * 64 + rb * 16 + hi * 4 + reg;
                float a = acc[rb][cb][reg] + bias;
                float g = 1.f / (1.f + __expf(-a));
                float h2v = (float)Hs[m][n];
                Hs[m][n] = (f16)(g * h2v);
            }
        }
    }
    __syncthreads();

    // ---- LayerNorm + score + VO write; wave wid owns rows wid*16..+15 ----
    {
        f32x4 gm = *(const f32x4*)&gamma[v * H_N + lane * 4];
        f32x4 bt = *(const f32x4*)&beta[v * H_N + lane * 4];
        f32x4 wa = *(const f32x4*)&Wa[lane * 4];
        float bav = ba[0];
        #pragma unroll
        for (int i = 0; i < 16; ++i) {
            int row = (wid << 4) + i;
            f16x4 gv = *(const f16x4*)&Hs[row][lane * 4];
            float g0 = gv[0], g1 = gv[1], g2 = gv[2], g3 = gv[3];
            float s = g0 + g1 + g2 + g3;
            float q = g0 * g0 + g1 * g1 + g2 * g2 + g3 * g3;
            #pragma unroll
            for (int mm = 1; mm < 64; mm <<= 1) {
                s += __shfl_xor(s, mm, 64);
                q += __shfl_xor(q, mm, 64);
            }
            float mu = s * (1.f / 256.f);
            float var = q * (1.f / 256.f) - mu * mu;
            float inv = rsqrtf(var + LN_EPS_F);
            float o0 = (g0 - mu) * inv * gm[0] + bt[0];
            float o1 = (g1 - mu) * inv * gm[1] + bt[1];
            float o2 = (g2 - mu) * inv * gm[2] + bt[2];
            float o3 = (g3 - mu) * inv * gm[3] + bt[3];
            f16x4 ov = { (f16)o0, (f16)o1, (f16)o2, (f16)o3 };
            *(f16x4*)&VO[((size_t)v * T_TOK + m0 + row) * H_N + lane * 4] = ov;
            float sp = o0 * wa[0] + o1 * wa[1] + o2 * wa[2] + o3 * wa[3];
            #pragma unroll
            for (int mm = 1; mm < 64; mm <<= 1) sp += __shfl_xor(sp, mm, 64);
            if (lane == 0) scores[(size_t)(m0 + row) * V_N + v] = sp + bav;
        }
    }
#undef GEMM_STEP
}

// ---------------- softmax over V + pooled sum (f16x2 vectorized) ----------------
__global__ __launch_bounds__(128) void pool(
    const f16* __restrict__ VO,       // [V][T][H]
    const float* __restrict__ scores, // [T][V]
    float* __restrict__ out)          // [T*H] vsn, then [T*V] attn
{
    int t = blockIdx.x, tid = threadIdx.x;
    __shared__ float sc[V_N];
    if (tid < V_N) sc[tid] = scores[t * V_N + tid];
    __syncthreads();
    float mx = -1e30f;
    #pragma unroll
    for (int v = 0; v < V_N; ++v) mx = fmaxf(mx, sc[v]);
    float e[V_N];
    float sum = 0.f;
    #pragma unroll
    for (int v = 0; v < V_N; ++v) { e[v] = __expf(sc[v] - mx); sum += e[v]; }
    float isum = 1.f / sum;
    float a0 = 0.f, a1 = 0.f;
    #pragma unroll
    for (int v = 0; v < V_N; ++v) {
        f16x2 vv = *(const f16x2*)&VO[((size_t)v * T_TOK + t) * H_N + tid * 2];
        float w = e[v] * isum;
        a0 = fmaf((float)vv[0], w, a0);
        a1 = fmaf((float)vv[1], w, a1);
    }
    *(float2*)&out[(size_t)t * H_N + tid * 2] = make_float2(a0, a1);
    if (tid < V_N)
        out[(size_t)T_TOK * H_N + (size_t)t * V_N + tid] = e[tid] * isum;
}

extern "C" void kernel_launch(void* const* d_in, const int* in_sizes, int n_in,
                              void* d_out, int out_size, void* d_ws, size_t ws_size,
                              hipStream_t stream)
{
    const float* x     = (const float*)d_in[0];
    const float* W1    = (const float*)d_in[1];
    const float* b1    = (const float*)d_in[2];
    const float* W2    = (const float*)d_in[3];
    const float* b2    = (const float*)d_in[4];
    const float* Wg    = (const float*)d_in[5];
    const float* bg    = (const float*)d_in[6];
    const float* gamma = (const float*)d_in[7];
    const float* beta  = (const float*)d_in[8];
    const float* Wa    = (const float*)d_in[9];
    const float* ba    = (const float*)d_in[10];
    float* out = (float*)d_out;

    char* ws = (char*)d_ws;
    f16* W2t = (f16*)ws;                               // 4 MB
    f16* Wgt = (f16*)(ws + ((size_t)4 << 20));         // 4 MB
    f16* VO  = (f16*)(ws + ((size_t)8 << 20));         // 64 MB
    float* scores = (float*)(ws + ((size_t)72 << 20)); // 0.5 MB

    prep_transpose<<<1024, 256, 0, stream>>>(W2, Wg, W2t, Wgt);
    fused_grn<<<1024, 512, 0, stream>>>(x, W1, b1, W2t, b2, Wgt, bg,
                                        gamma, beta, Wa, ba, VO, scores);
    pool<<<4096, 128, 0, stream>>>(VO, scores, out);
}